// Round 1
// baseline (1025.880 us; speedup 1.0000x reference)
//
#include <hip/hip_runtime.h>
#include <math.h>

#define D 50
#define T 20
#define BATCH 1024
#define S1S2 1000
#define DEG 50
#define NITEMS 50000
#define NLOGITS 49999   // item_emb[1:]

__device__ __forceinline__ float sigf(float x) { return 1.0f / (1.0f + expf(-x)); }

// ---------------- Kernel A: main LSTM over sessions, keep last hidden -------
// one block (256 thr) per session; W rows in VGPRs; x/h broadcast via LDS
__global__ __launch_bounds__(256) void lstm_main_kernel(
    const int* __restrict__ sess,        // [B,T]
    const float* __restrict__ item_emb,  // [NITEMS,D]
    const float* __restrict__ W_ih,      // [4D,D]
    const float* __restrict__ W_hh,      // [4D,D]
    const float* __restrict__ b_ih,
    const float* __restrict__ b_hh,
    float* __restrict__ out_h)           // [B,D]
{
    const int b = blockIdx.x;
    const int t = threadIdx.x;
    __shared__ float x_s[D];
    __shared__ float h_s[D];
    __shared__ float g_s[4 * D];
    __shared__ int idx_s[T];

    if (t < T) idx_s[t] = sess[b * T + t];

    float wih[D], whh[D];
    float bias = 0.f;
    if (t < 4 * D) {
        #pragma unroll
        for (int k = 0; k < D; ++k) {
            wih[k] = W_ih[t * D + k];
            whh[k] = W_hh[t * D + k];
        }
        bias = b_ih[t] + b_hh[t];
    }
    float c = 0.f;
    if (t < D) h_s[t] = 0.f;
    __syncthreads();

    for (int step = 0; step < T; ++step) {
        if (t < D) x_s[t] = item_emb[(size_t)idx_s[step] * D + t];
        __syncthreads();
        if (t < 4 * D) {
            float g = bias;
            #pragma unroll
            for (int k = 0; k < D; ++k)
                g += wih[k] * x_s[k] + whh[k] * h_s[k];
            g_s[t] = g;
        }
        __syncthreads();
        if (t < D) {
            float ig = sigf(g_s[t]);
            float fg = sigf(g_s[D + t]);
            float gg = tanhf(g_s[2 * D + t]);
            float og = sigf(g_s[3 * D + t]);
            c = fg * c + ig * gg;
            h_s[t] = og * tanhf(c);
        }
        __syncthreads();
    }
    if (t < D) out_h[b * D + t] = h_s[t];
}

// ---------------- Kernel B: friends single LSTM step + ls1 = relu(cat@W1^T) --
__global__ __launch_bounds__(256) void friends_kernel(
    const int* __restrict__ nodes,       // [S1S2]
    const int* __restrict__ fsess,       // [S1S2,T]
    const float* __restrict__ user_emb,  // [NUSERS,D]
    const float* __restrict__ item_emb,
    const float* __restrict__ W_ih,
    const float* __restrict__ W_hh,
    const float* __restrict__ b_ih,
    const float* __restrict__ b_hh,
    const float* __restrict__ W1,        // [D,2D]
    float* __restrict__ ls1)             // [S1S2,D]
{
    const int s = blockIdx.x;
    const int t = threadIdx.x;
    __shared__ float x_s[D];
    __shared__ float h_s[D];
    __shared__ float g_s[4 * D];

    if (t < D) x_s[t] = item_emb[(size_t)fsess[s * T] * D + t];
    __syncthreads();
    if (t < 4 * D) {
        float g = b_ih[t] + b_hh[t];
        #pragma unroll
        for (int k = 0; k < D; ++k) g += W_ih[t * D + k] * x_s[k];
        g_s[t] = g;
    }
    __syncthreads();
    if (t < D) {
        float ig = sigf(g_s[t]);
        float gg = tanhf(g_s[2 * D + t]);
        float og = sigf(g_s[3 * D + t]);
        float c1 = ig * gg;               // f*c0 = 0
        h_s[t] = og * tanhf(c1);
    }
    __syncthreads();
    if (t < D) {
        const int node = nodes[s];
        const float* ue = user_emb + (size_t)node * D;
        const float* w1r = W1 + t * 2 * D;
        float acc = 0.f;
        #pragma unroll
        for (int k = 0; k < D; ++k) acc += ue[k] * w1r[k];
        #pragma unroll
        for (int k = 0; k < D; ++k) acc += h_s[k] * w1r[D + k];
        ls1[s * D + t] = fmaxf(acc, 0.f);
    }
}

// ---------------- Kernel C: GAT (per-dst softmax over 50 edges) + sr --------
// edge_dst is repeat(arange(B), DEG): dst b owns edges [b*DEG, (b+1)*DEG)
__global__ __launch_bounds__(64) void gat_sr_kernel(
    const float* __restrict__ out_h,     // [B,D]
    const float* __restrict__ ls1,       // [S1S2,D]
    const int* __restrict__ edge_src,    // [B*DEG]
    const float* __restrict__ fc_W,      // [D,D]
    const float* __restrict__ fc_b,      // [D]
    const float* __restrict__ W2,        // [D,3D]
    float* __restrict__ sr)              // [B,D]
{
    const int b = blockIdx.x;
    const int l = threadIdx.x;
    __shared__ float q[D];
    __shared__ int srcs[DEG];
    __shared__ float w_s[DEG];
    __shared__ float a_s[D];
    __shared__ float g_s[D];

    if (l < D) q[l] = out_h[b * D + l];
    if (l < DEG) srcs[l] = edge_src[b * DEG + l];
    __syncthreads();

    float sc = -INFINITY;
    if (l < DEG) {
        const float* row = ls1 + (size_t)srcs[l] * D;
        float s = 0.f;
        #pragma unroll
        for (int k = 0; k < D; ++k) s += row[k] * q[k];
        sc = s;
    }
    float m = sc;
    #pragma unroll
    for (int off = 32; off; off >>= 1) m = fmaxf(m, __shfl_xor(m, off));
    float ex = (l < DEG) ? expf(sc - m) : 0.f;
    float den = ex;
    #pragma unroll
    for (int off = 32; off; off >>= 1) den += __shfl_xor(den, off);
    if (l < DEG) w_s[l] = ex / den;
    __syncthreads();

    if (l < D) {
        float a = 0.f;
        #pragma unroll
        for (int j = 0; j < DEG; ++j) a += w_s[j] * ls1[(size_t)srcs[j] * D + l];
        a_s[l] = a;
    }
    __syncthreads();
    if (l < D) {
        float g = fc_b[l];
        #pragma unroll
        for (int k = 0; k < D; ++k) g += a_s[k] * fc_W[l * D + k];
        g_s[l] = fmaxf(g, 0.f);
    }
    __syncthreads();
    if (l < D) {
        const float* w2r = W2 + l * 3 * D;
        float v = 0.f;
        #pragma unroll
        for (int k = 0; k < D; ++k) v += q[k] * (w2r[k] + w2r[D + k]);
        #pragma unroll
        for (int k = 0; k < D; ++k) v += g_s[k] * w2r[2 * D + k];
        sr[b * D + l] = v;
    }
}

// ---------------- Kernel D: logits = sr @ item_emb[1:]^T  (the big one) -----
// 64b x 128i tile per 256-thread block; 8b x 4i register tile per thread
#define TI 128
#define TBB 64
#define LSTR 27   // float2 stride (54 floats): odd*2 -> 2-way bank conflict max
__global__ __launch_bounds__(256) void logits_kernel(
    const float* __restrict__ sr,        // [B,D]
    const float* __restrict__ item_emb,  // [NITEMS,D]
    float* __restrict__ out)             // [B,NLOGITS]
{
    const int ib0 = blockIdx.x * TBB;
    const int ii0 = blockIdx.y * TI;
    const int t = threadIdx.x;
    __shared__ float2 srl[TBB * LSTR];
    __shared__ float2 itl[TI * LSTR];

    for (int idx = t; idx < TBB * 25; idx += 256) {
        int r = idx / 25, c2 = idx % 25;
        srl[r * LSTR + c2] = ((const float2*)sr)[(ib0 + r) * 25 + c2];
    }
    const int rows = min(TI, NLOGITS - ii0);
    for (int idx = t; idx < TI * 25; idx += 256) {
        int r = idx / 25, c2 = idx % 25;
        float2 v = make_float2(0.f, 0.f);
        if (r < rows) v = ((const float2*)item_emb)[(size_t)(1 + ii0 + r) * 25 + c2];
        itl[r * LSTR + c2] = v;
    }
    __syncthreads();

    const int tx = t & 31;   // i-dim
    const int ty = t >> 5;   // b-dim
    float acc[8][4];
    #pragma unroll
    for (int j = 0; j < 8; ++j)
        #pragma unroll
        for (int i = 0; i < 4; ++i) acc[j][i] = 0.f;

    #pragma unroll
    for (int k2 = 0; k2 < 25; ++k2) {
        float2 sv[8], iv[4];
        #pragma unroll
        for (int j = 0; j < 8; ++j) sv[j] = srl[(ty + 8 * j) * LSTR + k2];
        #pragma unroll
        for (int i = 0; i < 4; ++i) iv[i] = itl[(tx + 32 * i) * LSTR + k2];
        #pragma unroll
        for (int j = 0; j < 8; ++j)
            #pragma unroll
            for (int i = 0; i < 4; ++i)
                acc[j][i] += sv[j].x * iv[i].x + sv[j].y * iv[i].y;
    }

    #pragma unroll
    for (int j = 0; j < 8; ++j) {
        const size_t base = (size_t)(ib0 + ty + 8 * j) * NLOGITS + ii0;
        #pragma unroll
        for (int i = 0; i < 4; ++i) {
            int ii = tx + 32 * i;
            if (ii < rows) out[base + ii] = acc[j][i];
        }
    }
}

extern "C" void kernel_launch(void* const* d_in, const int* in_sizes, int n_in,
                              void* d_out, int out_size, void* d_ws, size_t ws_size,
                              hipStream_t stream) {
    const int*   sess      = (const int*)d_in[0];    // [B,T]
    const int*   nodes     = (const int*)d_in[1];    // [S1S2]
    const int*   fsess     = (const int*)d_in[2];    // [S1S2,T]
    const int*   edge_src  = (const int*)d_in[3];    // [E]
    // d_in[4] edge_dst: known structure repeat(arange(B), DEG)
    const float* user_emb  = (const float*)d_in[5];
    const float* item_emb  = (const float*)d_in[6];
    const float* W_ih      = (const float*)d_in[7];
    const float* W_hh      = (const float*)d_in[8];
    const float* b_ih      = (const float*)d_in[9];
    const float* b_hh      = (const float*)d_in[10];
    const float* W1        = (const float*)d_in[11];
    const float* fc_W      = (const float*)d_in[12];
    const float* fc_b      = (const float*)d_in[13];
    const float* W2        = (const float*)d_in[14];
    float* out = (float*)d_out;

    char* ws = (char*)d_ws;
    float* out_h = (float*)(ws);                    // [B,D]    204800 B
    float* ls1   = (float*)(ws + 204800);           // [S1S2,D] 200000 B
    float* sr    = (float*)(ws + 404800);           // [B,D]    204800 B

    hipLaunchKernelGGL(lstm_main_kernel, dim3(BATCH), dim3(256), 0, stream,
                       sess, item_emb, W_ih, W_hh, b_ih, b_hh, out_h);
    hipLaunchKernelGGL(friends_kernel, dim3(S1S2), dim3(256), 0, stream,
                       nodes, fsess, user_emb, item_emb, W_ih, W_hh, b_ih, b_hh, W1, ls1);
    hipLaunchKernelGGL(gat_sr_kernel, dim3(BATCH), dim3(64), 0, stream,
                       out_h, ls1, edge_src, fc_W, fc_b, W2, sr);
    hipLaunchKernelGGL(logits_kernel, dim3(BATCH / TBB, (NLOGITS + TI - 1) / TI), dim3(256), 0, stream,
                       sr, item_emb, out);
}

// Round 2
// 174.016 us; speedup vs baseline: 5.8953x; 5.8953x over previous
//
#include <hip/hip_runtime.h>
#include <math.h>

#define D 50
#define T 20
#define BATCH 1024
#define S1S2 1000
#define DEG 50
#define NITEMS 50000
#define NLOGITS 49999   // item_emb[1:]

__device__ __forceinline__ float sigf(float x) { return 1.0f / (1.0f + expf(-x)); }

// ---------------- Kernel A: main LSTM over sessions, keep last hidden -------
__global__ __launch_bounds__(256) void lstm_main_kernel(
    const int* __restrict__ sess,        // [B,T]
    const float* __restrict__ item_emb,  // [NITEMS,D]
    const float* __restrict__ W_ih,      // [4D,D]
    const float* __restrict__ W_hh,      // [4D,D]
    const float* __restrict__ b_ih,
    const float* __restrict__ b_hh,
    float* __restrict__ out_h)           // [B,D]
{
    const int b = blockIdx.x;
    const int t = threadIdx.x;
    __shared__ float x_s[D];
    __shared__ float h_s[D];
    __shared__ float g_s[4 * D];
    __shared__ int idx_s[T];

    if (t < T) idx_s[t] = sess[b * T + t];

    float wih[D], whh[D];
    float bias = 0.f;
    if (t < 4 * D) {
        #pragma unroll
        for (int k = 0; k < D; ++k) {
            wih[k] = W_ih[t * D + k];
            whh[k] = W_hh[t * D + k];
        }
        bias = b_ih[t] + b_hh[t];
    }
    float c = 0.f;
    if (t < D) h_s[t] = 0.f;
    __syncthreads();

    for (int step = 0; step < T; ++step) {
        if (t < D) x_s[t] = item_emb[(size_t)idx_s[step] * D + t];
        __syncthreads();
        if (t < 4 * D) {
            float g = bias;
            #pragma unroll
            for (int k = 0; k < D; ++k)
                g += wih[k] * x_s[k] + whh[k] * h_s[k];
            g_s[t] = g;
        }
        __syncthreads();
        if (t < D) {
            float ig = sigf(g_s[t]);
            float fg = sigf(g_s[D + t]);
            float gg = tanhf(g_s[2 * D + t]);
            float og = sigf(g_s[3 * D + t]);
            c = fg * c + ig * gg;
            h_s[t] = og * tanhf(c);
        }
        __syncthreads();
    }
    if (t < D) out_h[b * D + t] = h_s[t];
}

// ---------------- Kernel B: friends single LSTM step + ls1 = relu(cat@W1^T) --
__global__ __launch_bounds__(256) void friends_kernel(
    const int* __restrict__ nodes,       // [S1S2]
    const int* __restrict__ fsess,       // [S1S2,T]
    const float* __restrict__ user_emb,  // [NUSERS,D]
    const float* __restrict__ item_emb,
    const float* __restrict__ W_ih,
    const float* __restrict__ W_hh,
    const float* __restrict__ b_ih,
    const float* __restrict__ b_hh,
    const float* __restrict__ W1,        // [D,2D]
    float* __restrict__ ls1)             // [S1S2,D]
{
    const int s = blockIdx.x;
    const int t = threadIdx.x;
    __shared__ float x_s[D];
    __shared__ float h_s[D];
    __shared__ float g_s[4 * D];

    if (t < D) x_s[t] = item_emb[(size_t)fsess[s * T] * D + t];
    __syncthreads();
    if (t < 4 * D) {
        float g = b_ih[t] + b_hh[t];
        #pragma unroll
        for (int k = 0; k < D; ++k) g += W_ih[t * D + k] * x_s[k];
        g_s[t] = g;
    }
    __syncthreads();
    if (t < D) {
        float ig = sigf(g_s[t]);
        float gg = tanhf(g_s[2 * D + t]);
        float og = sigf(g_s[3 * D + t]);
        float c1 = ig * gg;               // f*c0 = 0
        h_s[t] = og * tanhf(c1);
    }
    __syncthreads();
    if (t < D) {
        const int node = nodes[s];
        const float* ue = user_emb + (size_t)node * D;
        const float* w1r = W1 + t * 2 * D;
        float acc = 0.f;
        #pragma unroll
        for (int k = 0; k < D; ++k) acc += ue[k] * w1r[k];
        #pragma unroll
        for (int k = 0; k < D; ++k) acc += h_s[k] * w1r[D + k];
        ls1[s * D + t] = fmaxf(acc, 0.f);
    }
}

// ---------------- Kernel C: GAT (per-dst softmax over 50 edges) + sr --------
__global__ __launch_bounds__(64) void gat_sr_kernel(
    const float* __restrict__ out_h,     // [B,D]
    const float* __restrict__ ls1,       // [S1S2,D]
    const int* __restrict__ edge_src,    // [B*DEG]
    const float* __restrict__ fc_W,      // [D,D]
    const float* __restrict__ fc_b,      // [D]
    const float* __restrict__ W2,        // [D,3D]
    float* __restrict__ sr)              // [B,D]
{
    const int b = blockIdx.x;
    const int l = threadIdx.x;
    __shared__ float q[D];
    __shared__ int srcs[DEG];
    __shared__ float w_s[DEG];
    __shared__ float a_s[D];
    __shared__ float g_s[D];

    if (l < D) q[l] = out_h[b * D + l];
    if (l < DEG) srcs[l] = edge_src[b * DEG + l];
    __syncthreads();

    float sc = -INFINITY;
    if (l < DEG) {
        const float* row = ls1 + (size_t)srcs[l] * D;
        float s = 0.f;
        #pragma unroll
        for (int k = 0; k < D; ++k) s += row[k] * q[k];
        sc = s;
    }
    float m = sc;
    #pragma unroll
    for (int off = 32; off; off >>= 1) m = fmaxf(m, __shfl_xor(m, off));
    float ex = (l < DEG) ? expf(sc - m) : 0.f;
    float den = ex;
    #pragma unroll
    for (int off = 32; off; off >>= 1) den += __shfl_xor(den, off);
    if (l < DEG) w_s[l] = ex / den;
    __syncthreads();

    if (l < D) {
        float a = 0.f;
        #pragma unroll
        for (int j = 0; j < DEG; ++j) a += w_s[j] * ls1[(size_t)srcs[j] * D + l];
        a_s[l] = a;
    }
    __syncthreads();
    if (l < D) {
        float g = fc_b[l];
        #pragma unroll
        for (int k = 0; k < D; ++k) g += a_s[k] * fc_W[l * D + k];
        g_s[l] = fmaxf(g, 0.f);
    }
    __syncthreads();
    if (l < D) {
        const float* w2r = W2 + l * 3 * D;
        float v = 0.f;
        #pragma unroll
        for (int k = 0; k < D; ++k) v += q[k] * (w2r[k] + w2r[D + k]);
        #pragma unroll
        for (int k = 0; k < D; ++k) v += g_s[k] * w2r[2 * D + k];
        sr[b * D + l] = v;
    }
}

// ---------------- Kernel D: logits = sr @ item_emb[1:]^T  -------------------
// 64b x 128i tile, 256 threads. Thread owns 8 rows x 4 CONSECUTIVE cols ->
// float4 stores, 512B contiguous per half-wave per row (fixes RMW writes).
// Item tile in LDS k-major with column interleave: col i at slot
// (i&3)*32 + (i>>2), row stride 130 float2 -> main-loop reads lane-stride-1.
#define TI 128
#define TBB 64
#define ITSTR 130   // float2 stride per k2
#define SRSTR 27    // float2 stride per sr row
__global__ __launch_bounds__(256) void logits_kernel(
    const float* __restrict__ sr,        // [B,D]
    const float* __restrict__ item_emb,  // [NITEMS,D]
    float* __restrict__ out)             // [B,NLOGITS]
{
    const int ib0 = blockIdx.x * TBB;
    const int ii0 = blockIdx.y * TI;
    const int t = threadIdx.x;
    __shared__ float2 it_s[25 * ITSTR];  // 26 KB
    __shared__ float2 sr_s[TBB * SRSTR]; // 13.8 KB

    // stage sr tile [64 rows][25 float2]
    for (int idx = t; idx < TBB * 25; idx += 256) {
        int r = idx / 25, c2 = idx % 25;
        sr_s[r * SRSTR + c2] = ((const float2*)sr)[(ib0 + r) * 25 + c2];
    }
    // stage item tile, interleaved: row r -> slot (r&3)*32 + (r>>2)
    const int rem = NLOGITS - ii0;           // valid cols in this tile
    for (int idx = t; idx < TI * 25; idx += 256) {
        int r = idx / 25, c2 = idx % 25;
        float2 v = make_float2(0.f, 0.f);
        if (r < rem) v = ((const float2*)item_emb)[(size_t)(1 + ii0 + r) * 25 + c2];
        it_s[c2 * ITSTR + (r & 3) * 32 + (r >> 2)] = v;
    }
    __syncthreads();

    const int tx = t & 31;   // col group: cols 4*tx .. 4*tx+3
    const int ty = t >> 5;   // row: ty + 8*j
    float acc[8][4];
    #pragma unroll
    for (int j = 0; j < 8; ++j)
        #pragma unroll
        for (int i = 0; i < 4; ++i) acc[j][i] = 0.f;

    #pragma unroll 5
    for (int k2 = 0; k2 < 25; ++k2) {
        float2 iv[4], sv[8];
        #pragma unroll
        for (int i = 0; i < 4; ++i) iv[i] = it_s[k2 * ITSTR + i * 32 + tx];
        #pragma unroll
        for (int j = 0; j < 8; ++j) sv[j] = sr_s[(ty + 8 * j) * SRSTR + k2];
        #pragma unroll
        for (int j = 0; j < 8; ++j)
            #pragma unroll
            for (int i = 0; i < 4; ++i)
                acc[j][i] += sv[j].x * iv[i].x + sv[j].y * iv[i].y;
    }

    const int c0 = 4 * tx;               // tile-local first col
    #pragma unroll
    for (int j = 0; j < 8; ++j) {
        const size_t base = (size_t)(ib0 + ty + 8 * j) * NLOGITS + ii0;
        if (c0 + 3 < rem) {
            float4 v = make_float4(acc[j][0], acc[j][1], acc[j][2], acc[j][3]);
            *(float4*)(out + base + c0) = v;
        } else {
            #pragma unroll
            for (int i = 0; i < 4; ++i)
                if (c0 + i < rem) out[base + c0 + i] = acc[j][i];
        }
    }
}

extern "C" void kernel_launch(void* const* d_in, const int* in_sizes, int n_in,
                              void* d_out, int out_size, void* d_ws, size_t ws_size,
                              hipStream_t stream) {
    const int*   sess      = (const int*)d_in[0];    // [B,T]
    const int*   nodes     = (const int*)d_in[1];    // [S1S2]
    const int*   fsess     = (const int*)d_in[2];    // [S1S2,T]
    const int*   edge_src  = (const int*)d_in[3];    // [E]
    // d_in[4] edge_dst: known structure repeat(arange(B), DEG)
    const float* user_emb  = (const float*)d_in[5];
    const float* item_emb  = (const float*)d_in[6];
    const float* W_ih      = (const float*)d_in[7];
    const float* W_hh      = (const float*)d_in[8];
    const float* b_ih      = (const float*)d_in[9];
    const float* b_hh      = (const float*)d_in[10];
    const float* W1        = (const float*)d_in[11];
    const float* fc_W      = (const float*)d_in[12];
    const float* fc_b      = (const float*)d_in[13];
    const float* W2        = (const float*)d_in[14];
    float* out = (float*)d_out;

    char* ws = (char*)d_ws;
    float* out_h = (float*)(ws);                    // [B,D]    204800 B
    float* ls1   = (float*)(ws + 204800);           // [S1S2,D] 200000 B
    float* sr    = (float*)(ws + 404800);           // [B,D]    204800 B

    hipLaunchKernelGGL(lstm_main_kernel, dim3(BATCH), dim3(256), 0, stream,
                       sess, item_emb, W_ih, W_hh, b_ih, b_hh, out_h);
    hipLaunchKernelGGL(friends_kernel, dim3(S1S2), dim3(256), 0, stream,
                       nodes, fsess, user_emb, item_emb, W_ih, W_hh, b_ih, b_hh, W1, ls1);
    hipLaunchKernelGGL(gat_sr_kernel, dim3(BATCH), dim3(64), 0, stream,
                       out_h, ls1, edge_src, fc_W, fc_b, W2, sr);
    hipLaunchKernelGGL(logits_kernel, dim3(BATCH / TBB, (NLOGITS + TI - 1) / TI), dim3(256), 0, stream,
                       sr, item_emb, out);
}

// Round 3
// 141.837 us; speedup vs baseline: 7.2328x; 1.2269x over previous
//
#include <hip/hip_runtime.h>
#include <math.h>

#define D 50
#define T 20
#define BATCH 1024
#define S1S2 1000
#define DEG 50
#define NITEMS 50000
#define NLOGITS 49999   // item_emb[1:]
#define KPAD 64         // K=50 padded to 64 for 2x mfma_16x16x32
#define NIPAD 50048     // item rows padded to multiple of 16
#define ICH 8           // i-tiles (of 16 cols) per wave

using bf16x8 = __attribute__((ext_vector_type(8))) __bf16;
using f32x4  = __attribute__((ext_vector_type(4))) float;

__device__ __forceinline__ float sigf(float x) { return 1.0f / (1.0f + expf(-x)); }

__device__ __forceinline__ unsigned short f2bf(float f) {
    unsigned u = __builtin_bit_cast(unsigned, f);
    u = (u + 0x7FFFu + ((u >> 16) & 1u)) >> 16;   // RNE
    return (unsigned short)u;
}

// ---------------- Kernel A: main LSTM over sessions, keep last hidden -------
__global__ __launch_bounds__(256) void lstm_main_kernel(
    const int* __restrict__ sess,        // [B,T]
    const float* __restrict__ item_emb,  // [NITEMS,D]
    const float* __restrict__ W_ih,      // [4D,D]
    const float* __restrict__ W_hh,      // [4D,D]
    const float* __restrict__ b_ih,
    const float* __restrict__ b_hh,
    float* __restrict__ out_h)           // [B,D]
{
    const int b = blockIdx.x;
    const int t = threadIdx.x;
    __shared__ float x_s[D];
    __shared__ float h_s[D];
    __shared__ float g_s[4 * D];
    __shared__ int idx_s[T];

    if (t < T) idx_s[t] = sess[b * T + t];

    float wih[D], whh[D];
    float bias = 0.f;
    if (t < 4 * D) {
        #pragma unroll
        for (int k = 0; k < D; ++k) {
            wih[k] = W_ih[t * D + k];
            whh[k] = W_hh[t * D + k];
        }
        bias = b_ih[t] + b_hh[t];
    }
    float c = 0.f;
    if (t < D) h_s[t] = 0.f;
    __syncthreads();

    for (int step = 0; step < T; ++step) {
        if (t < D) x_s[t] = item_emb[(size_t)idx_s[step] * D + t];
        __syncthreads();
        if (t < 4 * D) {
            float g = bias;
            #pragma unroll
            for (int k = 0; k < D; ++k)
                g += wih[k] * x_s[k] + whh[k] * h_s[k];
            g_s[t] = g;
        }
        __syncthreads();
        if (t < D) {
            float ig = sigf(g_s[t]);
            float fg = sigf(g_s[D + t]);
            float gg = tanhf(g_s[2 * D + t]);
            float og = sigf(g_s[3 * D + t]);
            c = fg * c + ig * gg;
            h_s[t] = og * tanhf(c);
        }
        __syncthreads();
    }
    if (t < D) out_h[b * D + t] = h_s[t];
}

// ---------------- Kernel B: friends single LSTM step + ls1 = relu(cat@W1^T) --
__global__ __launch_bounds__(256) void friends_kernel(
    const int* __restrict__ nodes,       // [S1S2]
    const int* __restrict__ fsess,       // [S1S2,T]
    const float* __restrict__ user_emb,  // [NUSERS,D]
    const float* __restrict__ item_emb,
    const float* __restrict__ W_ih,
    const float* __restrict__ W_hh,
    const float* __restrict__ b_ih,
    const float* __restrict__ b_hh,
    const float* __restrict__ W1,        // [D,2D]
    float* __restrict__ ls1)             // [S1S2,D]
{
    const int s = blockIdx.x;
    const int t = threadIdx.x;
    __shared__ float x_s[D];
    __shared__ float h_s[D];
    __shared__ float g_s[4 * D];

    if (t < D) x_s[t] = item_emb[(size_t)fsess[s * T] * D + t];
    __syncthreads();
    if (t < 4 * D) {
        float g = b_ih[t] + b_hh[t];
        #pragma unroll
        for (int k = 0; k < D; ++k) g += W_ih[t * D + k] * x_s[k];
        g_s[t] = g;
    }
    __syncthreads();
    if (t < D) {
        float ig = sigf(g_s[t]);
        float gg = tanhf(g_s[2 * D + t]);
        float og = sigf(g_s[3 * D + t]);
        float c1 = ig * gg;               // f*c0 = 0
        h_s[t] = og * tanhf(c1);
    }
    __syncthreads();
    if (t < D) {
        const int node = nodes[s];
        const float* ue = user_emb + (size_t)node * D;
        const float* w1r = W1 + t * 2 * D;
        float acc = 0.f;
        #pragma unroll
        for (int k = 0; k < D; ++k) acc += ue[k] * w1r[k];
        #pragma unroll
        for (int k = 0; k < D; ++k) acc += h_s[k] * w1r[D + k];
        ls1[s * D + t] = fmaxf(acc, 0.f);
    }
}

// ---------------- Kernel C: GAT + sr; emits K-padded bf16 sr ----------------
__global__ __launch_bounds__(64) void gat_sr_kernel(
    const float* __restrict__ out_h,     // [B,D]
    const float* __restrict__ ls1,       // [S1S2,D]
    const int* __restrict__ edge_src,    // [B*DEG]
    const float* __restrict__ fc_W,      // [D,D]
    const float* __restrict__ fc_b,      // [D]
    const float* __restrict__ W2,        // [D,3D]
    unsigned* __restrict__ sr_u)         // [B,KPAD/2] packed bf16 pairs
{
    const int b = blockIdx.x;
    const int l = threadIdx.x;
    __shared__ float q[D];
    __shared__ int srcs[DEG];
    __shared__ float w_s[DEG];
    __shared__ float a_s[D];
    __shared__ float g_s[D];
    __shared__ float srow_s[KPAD];

    srow_s[l] = 0.f;
    if (l < D) q[l] = out_h[b * D + l];
    if (l < DEG) srcs[l] = edge_src[b * DEG + l];
    __syncthreads();

    float sc = -INFINITY;
    if (l < DEG) {
        const float* row = ls1 + (size_t)srcs[l] * D;
        float s = 0.f;
        #pragma unroll
        for (int k = 0; k < D; ++k) s += row[k] * q[k];
        sc = s;
    }
    float m = sc;
    #pragma unroll
    for (int off = 32; off; off >>= 1) m = fmaxf(m, __shfl_xor(m, off));
    float ex = (l < DEG) ? expf(sc - m) : 0.f;
    float den = ex;
    #pragma unroll
    for (int off = 32; off; off >>= 1) den += __shfl_xor(den, off);
    if (l < DEG) w_s[l] = ex / den;
    __syncthreads();

    if (l < D) {
        float a = 0.f;
        #pragma unroll
        for (int j = 0; j < DEG; ++j) a += w_s[j] * ls1[(size_t)srcs[j] * D + l];
        a_s[l] = a;
    }
    __syncthreads();
    if (l < D) {
        float g = fc_b[l];
        #pragma unroll
        for (int k = 0; k < D; ++k) g += a_s[k] * fc_W[l * D + k];
        g_s[l] = fmaxf(g, 0.f);
    }
    __syncthreads();
    if (l < D) {
        const float* w2r = W2 + l * 3 * D;
        float v = 0.f;
        #pragma unroll
        for (int k = 0; k < D; ++k) v += q[k] * (w2r[k] + w2r[D + k]);
        #pragma unroll
        for (int k = 0; k < D; ++k) v += g_s[k] * w2r[2 * D + k];
        srow_s[l] = v;
    }
    __syncthreads();
    if (l < KPAD / 2) {
        unsigned u = (unsigned)f2bf(srow_s[2 * l]) |
                     ((unsigned)f2bf(srow_s[2 * l + 1]) << 16);
        sr_u[b * (KPAD / 2) + l] = u;
    }
}

// ---------------- Kernel P: pad+convert item_emb[1:] -> bf16 [NIPAD][KPAD] --
__global__ __launch_bounds__(256) void item_prep_kernel(
    const float* __restrict__ item_emb,  // [NITEMS,D]
    unsigned* __restrict__ item_u)       // [NIPAD][KPAD/2]
{
    const int idx = blockIdx.x * 256 + threadIdx.x;   // over NIPAD*32
    if (idx >= NIPAD * (KPAD / 2)) return;
    const int r = idx >> 5, c2 = idx & 31;
    const int c0 = c2 * 2, c1 = c0 + 1;
    float f0 = 0.f, f1 = 0.f;
    if (r < NLOGITS) {
        const float* row = item_emb + (size_t)(1 + r) * D;
        if (c0 < D) f0 = row[c0];
        if (c1 < D) f1 = row[c1];
    }
    item_u[idx] = (unsigned)f2bf(f0) | ((unsigned)f2bf(f1) << 16);
}

// ---------------- Kernel D: logits = sr_bf @ item_bf^T via MFMA -------------
// No LDS. Wave owns 64 batch-rows x ICH i-tiles of 16. A/B frags are direct
// 16B/lane global loads from the K-padded bf16 matrices (row stride 128B).
__global__ __launch_bounds__(256) void logits_mfma_kernel(
    const unsigned short* __restrict__ sr_bf,    // [BATCH][KPAD]
    const unsigned short* __restrict__ item_bf,  // [NIPAD][KPAD]
    float* __restrict__ out)                     // [B,NLOGITS]
{
    const int t = threadIdx.x;
    const int lane = t & 63;
    const int wave = t >> 6;
    const int b0 = blockIdx.x * 256 + wave * 64;   // this wave's first b-row
    const int r16 = lane & 15;
    const int g   = lane >> 4;

    // A frags: 4 m-tiles x 2 k-blocks; elem j of lane l = A[l&15][(l>>4)*8+j]
    bf16x8 a[4][2];
    #pragma unroll
    for (int m = 0; m < 4; ++m) {
        const unsigned short* ap = sr_bf + (size_t)(b0 + m * 16 + r16) * KPAD + g * 8;
        a[m][0] = *(const bf16x8*)(ap);
        a[m][1] = *(const bf16x8*)(ap + 32);
    }

    const int i_base = blockIdx.y * (16 * ICH);
    const int srow = g * 4;        // C/D: row = (lane>>4)*4 + reg
    const int scol = r16;          // C/D: col = lane & 15

    for (int it = 0; it < ICH; ++it) {
        const int i0 = i_base + it * 16;
        if (i0 >= NLOGITS) break;
        const unsigned short* bp = item_bf + (size_t)(i0 + r16) * KPAD + g * 8;
        bf16x8 bv0 = *(const bf16x8*)(bp);
        bf16x8 bv1 = *(const bf16x8*)(bp + 32);
        const int icol = i0 + scol;
        const bool iok = icol < NLOGITS;
        #pragma unroll
        for (int m = 0; m < 4; ++m) {
            f32x4 acc = {0.f, 0.f, 0.f, 0.f};
            acc = __builtin_amdgcn_mfma_f32_16x16x32_bf16(a[m][0], bv0, acc, 0, 0, 0);
            acc = __builtin_amdgcn_mfma_f32_16x16x32_bf16(a[m][1], bv1, acc, 0, 0, 0);
            if (iok) {
                float* op = out + (size_t)(b0 + m * 16 + srow) * NLOGITS + icol;
                #pragma unroll
                for (int r = 0; r < 4; ++r) op[(size_t)r * NLOGITS] = acc[r];
            }
        }
    }
}

extern "C" void kernel_launch(void* const* d_in, const int* in_sizes, int n_in,
                              void* d_out, int out_size, void* d_ws, size_t ws_size,
                              hipStream_t stream) {
    const int*   sess      = (const int*)d_in[0];    // [B,T]
    const int*   nodes     = (const int*)d_in[1];    // [S1S2]
    const int*   fsess     = (const int*)d_in[2];    // [S1S2,T]
    const int*   edge_src  = (const int*)d_in[3];    // [E]
    // d_in[4] edge_dst: known structure repeat(arange(B), DEG)
    const float* user_emb  = (const float*)d_in[5];
    const float* item_emb  = (const float*)d_in[6];
    const float* W_ih      = (const float*)d_in[7];
    const float* W_hh      = (const float*)d_in[8];
    const float* b_ih      = (const float*)d_in[9];
    const float* b_hh      = (const float*)d_in[10];
    const float* W1        = (const float*)d_in[11];
    const float* fc_W      = (const float*)d_in[12];
    const float* fc_b      = (const float*)d_in[13];
    const float* W2        = (const float*)d_in[14];
    float* out = (float*)d_out;

    char* ws = (char*)d_ws;
    float*    out_h  = (float*)(ws);                    // [B,D]        204800 B
    float*    ls1    = (float*)(ws + 204800);           // [S1S2,D]     200000 B
    unsigned* sr_u   = (unsigned*)(ws + 404800);        // [B,32]       131072 B
    unsigned* item_u = (unsigned*)(ws + 535872);        // [NIPAD,32]  6406144 B

    hipLaunchKernelGGL(item_prep_kernel,
                       dim3((NIPAD * (KPAD / 2) + 255) / 256), dim3(256), 0, stream,
                       item_emb, item_u);
    hipLaunchKernelGGL(lstm_main_kernel, dim3(BATCH), dim3(256), 0, stream,
                       sess, item_emb, W_ih, W_hh, b_ih, b_hh, out_h);
    hipLaunchKernelGGL(friends_kernel, dim3(S1S2), dim3(256), 0, stream,
                       nodes, fsess, user_emb, item_emb, W_ih, W_hh, b_ih, b_hh, W1, ls1);
    hipLaunchKernelGGL(gat_sr_kernel, dim3(BATCH), dim3(64), 0, stream,
                       out_h, ls1, edge_src, fc_W, fc_b, W2, sr_u);
    // grid.x = b-groups (adjacent blocks share the i-chunk -> L2 reuse of item rows)
    const int n_ichunks = (NLOGITS + 16 * ICH - 1) / (16 * ICH);
    hipLaunchKernelGGL(logits_mfma_kernel, dim3(BATCH / 256, n_ichunks), dim3(256), 0, stream,
                       (const unsigned short*)sr_u, (const unsigned short*)item_u, out);
}

// Round 4
// 125.570 us; speedup vs baseline: 8.1698x; 1.1295x over previous
//
#include <hip/hip_runtime.h>
#include <math.h>

#define D 50
#define T 20
#define BATCH 1024
#define S1S2 1000
#define DEG 50
#define NITEMS 50000
#define NLOGITS 49999   // item_emb[1:]
#define KPAD 64         // K=50 padded to 64 for 2x mfma_16x16x32
#define NIPAD 50048     // item rows padded to multiple of 64
#define LROW 520        // LDS row stride (floats) for 512-col C tile

using bf16x8 = __attribute__((ext_vector_type(8))) __bf16;
using f32x4  = __attribute__((ext_vector_type(4))) float;

__device__ __forceinline__ float sigf(float x) { return 1.0f / (1.0f + expf(-x)); }

__device__ __forceinline__ unsigned short f2bf(float f) {
    unsigned u = __builtin_bit_cast(unsigned, f);
    u = (u + 0x7FFFu + ((u >> 16) & 1u)) >> 16;   // RNE
    return (unsigned short)u;
}

// ---------------- Kernel A: main LSTM over sessions, keep last hidden -------
__global__ __launch_bounds__(256) void lstm_main_kernel(
    const int* __restrict__ sess,        // [B,T]
    const float* __restrict__ item_emb,  // [NITEMS,D]
    const float* __restrict__ W_ih,      // [4D,D]
    const float* __restrict__ W_hh,      // [4D,D]
    const float* __restrict__ b_ih,
    const float* __restrict__ b_hh,
    float* __restrict__ out_h)           // [B,D]
{
    const int b = blockIdx.x;
    const int t = threadIdx.x;
    __shared__ float x_s[D];
    __shared__ float h_s[D];
    __shared__ float g_s[4 * D];
    __shared__ int idx_s[T];

    if (t < T) idx_s[t] = sess[b * T + t];

    float wih[D], whh[D];
    float bias = 0.f;
    if (t < 4 * D) {
        #pragma unroll
        for (int k = 0; k < D; ++k) {
            wih[k] = W_ih[t * D + k];
            whh[k] = W_hh[t * D + k];
        }
        bias = b_ih[t] + b_hh[t];
    }
    float c = 0.f;
    if (t < D) h_s[t] = 0.f;
    __syncthreads();

    for (int step = 0; step < T; ++step) {
        if (t < D) x_s[t] = item_emb[(size_t)idx_s[step] * D + t];
        __syncthreads();
        if (t < 4 * D) {
            float g = bias;
            #pragma unroll
            for (int k = 0; k < D; ++k)
                g += wih[k] * x_s[k] + whh[k] * h_s[k];
            g_s[t] = g;
        }
        __syncthreads();
        if (t < D) {
            float ig = sigf(g_s[t]);
            float fg = sigf(g_s[D + t]);
            float gg = tanhf(g_s[2 * D + t]);
            float og = sigf(g_s[3 * D + t]);
            c = fg * c + ig * gg;
            h_s[t] = og * tanhf(c);
        }
        __syncthreads();
    }
    if (t < D) out_h[b * D + t] = h_s[t];
}

// ---------------- Kernel B: friends single LSTM step + ls1 = relu(cat@W1^T) --
__global__ __launch_bounds__(256) void friends_kernel(
    const int* __restrict__ nodes,       // [S1S2]
    const int* __restrict__ fsess,       // [S1S2,T]
    const float* __restrict__ user_emb,  // [NUSERS,D]
    const float* __restrict__ item_emb,
    const float* __restrict__ W_ih,
    const float* __restrict__ W_hh,
    const float* __restrict__ b_ih,
    const float* __restrict__ b_hh,
    const float* __restrict__ W1,        // [D,2D]
    float* __restrict__ ls1)             // [S1S2,D]
{
    const int s = blockIdx.x;
    const int t = threadIdx.x;
    __shared__ float x_s[D];
    __shared__ float h_s[D];
    __shared__ float g_s[4 * D];

    if (t < D) x_s[t] = item_emb[(size_t)fsess[s * T] * D + t];
    __syncthreads();
    if (t < 4 * D) {
        float g = b_ih[t] + b_hh[t];
        #pragma unroll
        for (int k = 0; k < D; ++k) g += W_ih[t * D + k] * x_s[k];
        g_s[t] = g;
    }
    __syncthreads();
    if (t < D) {
        float ig = sigf(g_s[t]);
        float gg = tanhf(g_s[2 * D + t]);
        float og = sigf(g_s[3 * D + t]);
        float c1 = ig * gg;               // f*c0 = 0
        h_s[t] = og * tanhf(c1);
    }
    __syncthreads();
    if (t < D) {
        const int node = nodes[s];
        const float* ue = user_emb + (size_t)node * D;
        const float* w1r = W1 + t * 2 * D;
        float acc = 0.f;
        #pragma unroll
        for (int k = 0; k < D; ++k) acc += ue[k] * w1r[k];
        #pragma unroll
        for (int k = 0; k < D; ++k) acc += h_s[k] * w1r[D + k];
        ls1[s * D + t] = fmaxf(acc, 0.f);
    }
}

// ---------------- Kernel C: GAT + sr; emits K-padded bf16 sr ----------------
__global__ __launch_bounds__(64) void gat_sr_kernel(
    const float* __restrict__ out_h,     // [B,D]
    const float* __restrict__ ls1,       // [S1S2,D]
    const int* __restrict__ edge_src,    // [B*DEG]
    const float* __restrict__ fc_W,      // [D,D]
    const float* __restrict__ fc_b,      // [D]
    const float* __restrict__ W2,        // [D,3D]
    unsigned* __restrict__ sr_u)         // [B,KPAD/2] packed bf16 pairs
{
    const int b = blockIdx.x;
    const int l = threadIdx.x;
    __shared__ float q[D];
    __shared__ int srcs[DEG];
    __shared__ float w_s[DEG];
    __shared__ float a_s[D];
    __shared__ float g_s[D];
    __shared__ float srow_s[KPAD];

    srow_s[l] = 0.f;
    if (l < D) q[l] = out_h[b * D + l];
    if (l < DEG) srcs[l] = edge_src[b * DEG + l];
    __syncthreads();

    float sc = -INFINITY;
    if (l < DEG) {
        const float* row = ls1 + (size_t)srcs[l] * D;
        float s = 0.f;
        #pragma unroll
        for (int k = 0; k < D; ++k) s += row[k] * q[k];
        sc = s;
    }
    float m = sc;
    #pragma unroll
    for (int off = 32; off; off >>= 1) m = fmaxf(m, __shfl_xor(m, off));
    float ex = (l < DEG) ? expf(sc - m) : 0.f;
    float den = ex;
    #pragma unroll
    for (int off = 32; off; off >>= 1) den += __shfl_xor(den, off);
    if (l < DEG) w_s[l] = ex / den;
    __syncthreads();

    if (l < D) {
        float a = 0.f;
        #pragma unroll
        for (int j = 0; j < DEG; ++j) a += w_s[j] * ls1[(size_t)srcs[j] * D + l];
        a_s[l] = a;
    }
    __syncthreads();
    if (l < D) {
        float g = fc_b[l];
        #pragma unroll
        for (int k = 0; k < D; ++k) g += a_s[k] * fc_W[l * D + k];
        g_s[l] = fmaxf(g, 0.f);
    }
    __syncthreads();
    if (l < D) {
        const float* w2r = W2 + l * 3 * D;
        float v = 0.f;
        #pragma unroll
        for (int k = 0; k < D; ++k) v += q[k] * (w2r[k] + w2r[D + k]);
        #pragma unroll
        for (int k = 0; k < D; ++k) v += g_s[k] * w2r[2 * D + k];
        srow_s[l] = v;
    }
    __syncthreads();
    if (l < KPAD / 2) {
        unsigned u = (unsigned)f2bf(srow_s[2 * l]) |
                     ((unsigned)f2bf(srow_s[2 * l + 1]) << 16);
        sr_u[b * (KPAD / 2) + l] = u;
    }
}

// ---------------- Kernel P: pad+convert item_emb[1:] -> bf16 [NIPAD][KPAD] --
__global__ __launch_bounds__(256) void item_prep_kernel(
    const float* __restrict__ item_emb,  // [NITEMS,D]
    unsigned* __restrict__ item_u)       // [NIPAD][KPAD/2]
{
    const int idx = blockIdx.x * 256 + threadIdx.x;   // over NIPAD*32
    if (idx >= NIPAD * (KPAD / 2)) return;
    const int r = idx >> 5, c2 = idx & 31;
    const int c0 = c2 * 2, c1 = c0 + 1;
    float f0 = 0.f, f1 = 0.f;
    if (r < NLOGITS) {
        const float* row = item_emb + (size_t)(1 + r) * D;
        if (c0 < D) f0 = row[c0];
        if (c1 < D) f1 = row[c1];
    }
    item_u[idx] = (unsigned)f2bf(f0) | ((unsigned)f2bf(f1) << 16);
}

// ---------------- Kernel D: logits = item_bf @ sr_bf^T via MFMA, LDS-staged C
// Block: 4 waves, tile = 16 batch-rows x 512 item-cols.
// MFMA: M = item (rows), N = batch (16 cols). Wave w owns i sub-range w*128.
// Epilogue: C restaged through LDS; stores are 1 KB contiguous per row per
// wave-instruction (float4/lane) -> no partial-sector write amplification.
__global__ __launch_bounds__(256) void logits_mfma_kernel(
    const unsigned short* __restrict__ sr_bf,    // [BATCH][KPAD]
    const unsigned short* __restrict__ item_bf,  // [NIPAD][KPAD]
    float* __restrict__ out)                     // [B,NLOGITS]
{
    const int t = threadIdx.x;
    const int lane = t & 63;
    const int wave = t >> 6;
    const int r16 = lane & 15;
    const int g   = lane >> 4;
    const int b0 = blockIdx.x * 16;
    const int ibase = blockIdx.y * 512;
    const int i0w = ibase + wave * 128;

    __shared__ float ls[16 * LROW];   // 33280 B

    // B fragment (N=batch): lane l holds col b0+(l&15), k elems (l>>4)*8+j
    const unsigned short* bp = sr_bf + (size_t)(b0 + r16) * KPAD + g * 8;
    bf16x8 bv0 = *(const bf16x8*)(bp);
    bf16x8 bv1 = *(const bf16x8*)(bp + 32);

    #pragma unroll
    for (int m = 0; m < 8; ++m) {
        int irow = i0w + m * 16 + r16;
        const unsigned short* ap =
            item_bf + (size_t)(irow < NIPAD ? irow : NIPAD - 1) * KPAD + g * 8;
        bf16x8 av0 = *(const bf16x8*)(ap);
        bf16x8 av1 = *(const bf16x8*)(ap + 32);
        f32x4 acc = {0.f, 0.f, 0.f, 0.f};
        acc = __builtin_amdgcn_mfma_f32_16x16x32_bf16(av0, bv0, acc, 0, 0, 0);
        acc = __builtin_amdgcn_mfma_f32_16x16x32_bf16(av1, bv1, acc, 0, 0, 0);
        // C: row(i-local) = g*4+reg, col(b-local) = r16
        *(f32x4*)&ls[r16 * LROW + wave * 128 + m * 16 + g * 4] = acc;
    }
    __syncthreads();

    // store: one full row x 1KB contiguous per wave-instruction
    #pragma unroll
    for (int pass = 0; pass < 4; ++pass) {
        const int row = wave * 4 + pass;
        float* orow = out + (size_t)(b0 + row) * NLOGITS + ibase;
        #pragma unroll
        for (int it2 = 0; it2 < 2; ++it2) {
            const int c = lane * 4 + it2 * 256;
            const int i = ibase + c;
            f32x4 v = *(const f32x4*)&ls[row * LROW + c];
            if (i + 3 < NLOGITS) {
                *(float4*)(orow + c) = make_float4(v[0], v[1], v[2], v[3]);
            } else {
                #pragma unroll
                for (int r = 0; r < 4; ++r)
                    if (i + r < NLOGITS) orow[c + r] = v[r];
            }
        }
    }
}

extern "C" void kernel_launch(void* const* d_in, const int* in_sizes, int n_in,
                              void* d_out, int out_size, void* d_ws, size_t ws_size,
                              hipStream_t stream) {
    const int*   sess      = (const int*)d_in[0];    // [B,T]
    const int*   nodes     = (const int*)d_in[1];    // [S1S2]
    const int*   fsess     = (const int*)d_in[2];    // [S1S2,T]
    const int*   edge_src  = (const int*)d_in[3];    // [E]
    // d_in[4] edge_dst: known structure repeat(arange(B), DEG)
    const float* user_emb  = (const float*)d_in[5];
    const float* item_emb  = (const float*)d_in[6];
    const float* W_ih      = (const float*)d_in[7];
    const float* W_hh      = (const float*)d_in[8];
    const float* b_ih      = (const float*)d_in[9];
    const float* b_hh      = (const float*)d_in[10];
    const float* W1        = (const float*)d_in[11];
    const float* fc_W      = (const float*)d_in[12];
    const float* fc_b      = (const float*)d_in[13];
    const float* W2        = (const float*)d_in[14];
    float* out = (float*)d_out;

    char* ws = (char*)d_ws;
    float*    out_h  = (float*)(ws);                    // [B,D]        204800 B
    float*    ls1    = (float*)(ws + 204800);           // [S1S2,D]     200000 B
    unsigned* sr_u   = (unsigned*)(ws + 404800);        // [B,32]       131072 B
    unsigned* item_u = (unsigned*)(ws + 535872);        // [NIPAD,32]  6406144 B

    hipLaunchKernelGGL(item_prep_kernel,
                       dim3((NIPAD * (KPAD / 2) + 255) / 256), dim3(256), 0, stream,
                       item_emb, item_u);
    hipLaunchKernelGGL(lstm_main_kernel, dim3(BATCH), dim3(256), 0, stream,
                       sess, item_emb, W_ih, W_hh, b_ih, b_hh, out_h);
    hipLaunchKernelGGL(friends_kernel, dim3(S1S2), dim3(256), 0, stream,
                       nodes, fsess, user_emb, item_emb, W_ih, W_hh, b_ih, b_hh, W1, ls1);
    hipLaunchKernelGGL(gat_sr_kernel, dim3(BATCH), dim3(64), 0, stream,
                       out_h, ls1, edge_src, fc_W, fc_b, W2, sr_u);
    // grid.x fastest over b-groups: the 64 blocks of one i-chunk are adjacent
    // -> item rows L2/L3-resident while all batches consume them
    hipLaunchKernelGGL(logits_mfma_kernel,
                       dim3(BATCH / 16, (NLOGITS + 511) / 512), dim3(256), 0, stream,
                       (const unsigned short*)sr_u, (const unsigned short*)item_u, out);
}

// Round 5
// 111.915 us; speedup vs baseline: 9.1666x; 1.1220x over previous
//
#include <hip/hip_runtime.h>
#include <math.h>

#define D 50
#define T 20
#define BATCH 1024
#define S1S2 1000
#define DEG 50
#define NITEMS 50000
#define NLOGITS 49999   // item_emb[1:]
#define KPAD 64         // K=50 padded to 64 for 2x mfma_16x16x32
#define NIPAD 50048     // item rows padded to multiple of 64
#define LROW 520        // LDS row stride (floats) for 512-col C tile
#define CHUNKS 98       // valid 512-col i-chunks
#define CHUNKS_PAD 104  // padded to 8*13 for XCD-contiguous swizzle
#define PREP_BLKS ((NIPAD * (KPAD / 2) + 255) / 256)   // 6256

using bf16x8 = __attribute__((ext_vector_type(8))) __bf16;
using f32x4  = __attribute__((ext_vector_type(4))) float;

__device__ __forceinline__ float sigf(float x) { return 1.0f / (1.0f + expf(-x)); }

__device__ __forceinline__ unsigned short f2bf(float f) {
    unsigned u = __builtin_bit_cast(unsigned, f);
    u = (u + 0x7FFFu + ((u >> 16) & 1u)) >> 16;   // RNE
    return (unsigned short)u;
}

// ---------------- Fused front kernel: lstm | friends | item_prep ------------
// blocks [0,BATCH): main LSTM; [BATCH,BATCH+S1S2): friends; rest: item prep.
__global__ __launch_bounds__(256) void fused_front_kernel(
    const int* __restrict__ sess,        // [B,T]
    const int* __restrict__ nodes,       // [S1S2]
    const int* __restrict__ fsess,       // [S1S2,T]
    const float* __restrict__ user_emb,
    const float* __restrict__ item_emb,  // [NITEMS,D]
    const float* __restrict__ W_ih,      // [4D,D]
    const float* __restrict__ W_hh,      // [4D,D]
    const float* __restrict__ b_ih,
    const float* __restrict__ b_hh,
    const float* __restrict__ W1,        // [D,2D]
    float* __restrict__ out_h,           // [B,D]
    float* __restrict__ ls1,             // [S1S2,D]
    unsigned* __restrict__ item_u)       // [NIPAD][KPAD/2]
{
    const int blk = blockIdx.x;
    const int t = threadIdx.x;

    if (blk < BATCH) {
        // ---------------- main LSTM, x prefetched one step ahead -----------
        const int b = blk;
        __shared__ float x_s[D];
        __shared__ float h_s[D];
        __shared__ float g_s[4 * D];
        __shared__ int idx_s[T];

        if (t < T) idx_s[t] = sess[b * T + t];

        float wih[D], whh[D];
        float bias = 0.f;
        if (t < 4 * D) {
            #pragma unroll
            for (int k = 0; k < D; ++k) {
                wih[k] = W_ih[t * D + k];
                whh[k] = W_hh[t * D + k];
            }
            bias = b_ih[t] + b_hh[t];
        }
        float c = 0.f;
        if (t < D) h_s[t] = 0.f;
        __syncthreads();                       // idx_s ready
        if (t < D) x_s[t] = item_emb[(size_t)idx_s[0] * D + t];
        __syncthreads();                       // x_s ready

        for (int step = 0; step < T; ++step) {
            float xn = 0.f;
            if (t < D && step + 1 < T)          // prefetch next x into reg
                xn = item_emb[(size_t)idx_s[step + 1] * D + t];
            if (t < 4 * D) {
                float g = bias;
                #pragma unroll
                for (int k = 0; k < D; ++k)
                    g += wih[k] * x_s[k] + whh[k] * h_s[k];
                g_s[t] = g;
            }
            __syncthreads();                   // g_s ready, x_s free
            if (t < D) {
                float ig = sigf(g_s[t]);
                float fg = sigf(g_s[D + t]);
                float gg = tanhf(g_s[2 * D + t]);
                float og = sigf(g_s[3 * D + t]);
                c = fg * c + ig * gg;
                h_s[t] = og * tanhf(c);
                if (step + 1 < T) x_s[t] = xn;
            }
            __syncthreads();
        }
        if (t < D) out_h[b * D + t] = h_s[t];
    } else if (blk < BATCH + S1S2) {
        // ---------------- friends: one LSTM step + relu(cat@W1^T) ----------
        const int s = blk - BATCH;
        __shared__ float fx_s[D];
        __shared__ float fh_s[D];
        __shared__ float fg_s[4 * D];

        if (t < D) fx_s[t] = item_emb[(size_t)fsess[s * T] * D + t];
        __syncthreads();
        if (t < 4 * D) {
            float g = b_ih[t] + b_hh[t];
            #pragma unroll
            for (int k = 0; k < D; ++k) g += W_ih[t * D + k] * fx_s[k];
            fg_s[t] = g;
        }
        __syncthreads();
        if (t < D) {
            float ig = sigf(fg_s[t]);
            float gg = tanhf(fg_s[2 * D + t]);
            float og = sigf(fg_s[3 * D + t]);
            float c1 = ig * gg;               // f*c0 = 0
            fh_s[t] = og * tanhf(c1);
        }
        __syncthreads();
        if (t < D) {
            const int node = nodes[s];
            const float* ue = user_emb + (size_t)node * D;
            const float* w1r = W1 + t * 2 * D;
            float acc = 0.f;
            #pragma unroll
            for (int k = 0; k < D; ++k) acc += ue[k] * w1r[k];
            #pragma unroll
            for (int k = 0; k < D; ++k) acc += fh_s[k] * w1r[D + k];
            ls1[s * D + t] = fmaxf(acc, 0.f);
        }
    } else {
        // ---------------- item prep: pad+convert to bf16 [NIPAD][KPAD] -----
        const int idx = (blk - BATCH - S1S2) * 256 + t;
        if (idx >= NIPAD * (KPAD / 2)) return;
        const int r = idx >> 5, c2 = idx & 31;
        const int c0 = c2 * 2, c1 = c0 + 1;
        float f0 = 0.f, f1 = 0.f;
        if (r < NLOGITS) {
            const float* row = item_emb + (size_t)(1 + r) * D;
            if (c0 < D) f0 = row[c0];
            if (c1 < D) f1 = row[c1];
        }
        item_u[idx] = (unsigned)f2bf(f0) | ((unsigned)f2bf(f1) << 16);
    }
}

// ---------------- Kernel C: GAT + sr; emits K-padded bf16 sr ----------------
__global__ __launch_bounds__(64) void gat_sr_kernel(
    const float* __restrict__ out_h,     // [B,D]
    const float* __restrict__ ls1,       // [S1S2,D]
    const int* __restrict__ edge_src,    // [B*DEG]
    const float* __restrict__ fc_W,      // [D,D]
    const float* __restrict__ fc_b,      // [D]
    const float* __restrict__ W2,        // [D,3D]
    unsigned* __restrict__ sr_u)         // [B,KPAD/2] packed bf16 pairs
{
    const int b = blockIdx.x;
    const int l = threadIdx.x;
    __shared__ float q[D];
    __shared__ int srcs[DEG];
    __shared__ float w_s[DEG];
    __shared__ float a_s[D];
    __shared__ float g_s[D];
    __shared__ float srow_s[KPAD];

    srow_s[l] = 0.f;
    if (l < D) q[l] = out_h[b * D + l];
    if (l < DEG) srcs[l] = edge_src[b * DEG + l];
    __syncthreads();

    float sc = -INFINITY;
    if (l < DEG) {
        const float* row = ls1 + (size_t)srcs[l] * D;
        float s = 0.f;
        #pragma unroll
        for (int k = 0; k < D; ++k) s += row[k] * q[k];
        sc = s;
    }
    float m = sc;
    #pragma unroll
    for (int off = 32; off; off >>= 1) m = fmaxf(m, __shfl_xor(m, off));
    float ex = (l < DEG) ? expf(sc - m) : 0.f;
    float den = ex;
    #pragma unroll
    for (int off = 32; off; off >>= 1) den += __shfl_xor(den, off);
    if (l < DEG) w_s[l] = ex / den;
    __syncthreads();

    if (l < D) {
        float a = 0.f;
        #pragma unroll
        for (int j = 0; j < DEG; ++j) a += w_s[j] * ls1[(size_t)srcs[j] * D + l];
        a_s[l] = a;
    }
    __syncthreads();
    if (l < D) {
        float g = fc_b[l];
        #pragma unroll
        for (int k = 0; k < D; ++k) g += a_s[k] * fc_W[l * D + k];
        g_s[l] = fmaxf(g, 0.f);
    }
    __syncthreads();
    if (l < D) {
        const float* w2r = W2 + l * 3 * D;
        float v = 0.f;
        #pragma unroll
        for (int k = 0; k < D; ++k) v += q[k] * (w2r[k] + w2r[D + k]);
        #pragma unroll
        for (int k = 0; k < D; ++k) v += g_s[k] * w2r[2 * D + k];
        srow_s[l] = v;
    }
    __syncthreads();
    if (l < KPAD / 2) {
        unsigned u = (unsigned)f2bf(srow_s[2 * l]) |
                     ((unsigned)f2bf(srow_s[2 * l + 1]) << 16);
        sr_u[b * (KPAD / 2) + l] = u;
    }
}

// ---------------- Kernel D: logits = item_bf @ sr_bf^T via MFMA, LDS-staged C
// 1-D grid, XCD-contiguous chunk swizzle: XCD k owns i-chunks [13k,13k+13)
// for ALL b-slabs -> its 832KB item slice stays L2-resident, and concurrent
// blocks on one XCD write CONTIGUOUS 26KB row segments (DRAM page locality)
// instead of ~500 scattered 2KB streams.
__global__ __launch_bounds__(256) void logits_mfma_kernel(
    const unsigned short* __restrict__ sr_bf,    // [BATCH][KPAD]
    const unsigned short* __restrict__ item_bf,  // [NIPAD][KPAD]
    float* __restrict__ out)                     // [B,NLOGITS]
{
    const int n = blockIdx.x;
    const int slab = n / CHUNKS_PAD;             // b-slab 0..63
    const int j = n - slab * CHUNKS_PAD;         // dispatch order in slab
    const int chunk = (j & 7) * 13 + (j >> 3);   // XCD-contiguous mapping
    if (chunk >= CHUNKS) return;

    const int t = threadIdx.x;
    const int lane = t & 63;
    const int wave = t >> 6;
    const int r16 = lane & 15;
    const int g   = lane >> 4;
    const int b0 = slab * 16;
    const int ibase = chunk * 512;
    const int i0w = ibase + wave * 128;

    __shared__ float ls[16 * LROW];   // 33280 B

    // B fragment (N=batch): lane l holds col b0+(l&15), k elems (l>>4)*8+j
    const unsigned short* bp = sr_bf + (size_t)(b0 + r16) * KPAD + g * 8;
    bf16x8 bv0 = *(const bf16x8*)(bp);
    bf16x8 bv1 = *(const bf16x8*)(bp + 32);

    #pragma unroll
    for (int m = 0; m < 8; ++m) {
        int irow = i0w + m * 16 + r16;
        const unsigned short* ap =
            item_bf + (size_t)(irow < NIPAD ? irow : NIPAD - 1) * KPAD + g * 8;
        bf16x8 av0 = *(const bf16x8*)(ap);
        bf16x8 av1 = *(const bf16x8*)(ap + 32);
        f32x4 acc = {0.f, 0.f, 0.f, 0.f};
        acc = __builtin_amdgcn_mfma_f32_16x16x32_bf16(av0, bv0, acc, 0, 0, 0);
        acc = __builtin_amdgcn_mfma_f32_16x16x32_bf16(av1, bv1, acc, 0, 0, 0);
        // C: row(i-local) = g*4+reg, col(b-local) = r16
        *(f32x4*)&ls[r16 * LROW + wave * 128 + m * 16 + g * 4] = acc;
    }
    __syncthreads();

    // store: one full row x 1KB contiguous per wave-instruction
    #pragma unroll
    for (int pass = 0; pass < 4; ++pass) {
        const int row = wave * 4 + pass;
        float* orow = out + (size_t)(b0 + row) * NLOGITS + ibase;
        #pragma unroll
        for (int it2 = 0; it2 < 2; ++it2) {
            const int c = lane * 4 + it2 * 256;
            const int i = ibase + c;
            f32x4 v = *(const f32x4*)&ls[row * LROW + c];
            if (i + 3 < NLOGITS) {
                *(float4*)(orow + c) = make_float4(v[0], v[1], v[2], v[3]);
            } else {
                #pragma unroll
                for (int r = 0; r < 4; ++r)
                    if (i + r < NLOGITS) orow[c + r] = v[r];
            }
        }
    }
}

extern "C" void kernel_launch(void* const* d_in, const int* in_sizes, int n_in,
                              void* d_out, int out_size, void* d_ws, size_t ws_size,
                              hipStream_t stream) {
    const int*   sess      = (const int*)d_in[0];    // [B,T]
    const int*   nodes     = (const int*)d_in[1];    // [S1S2]
    const int*   fsess     = (const int*)d_in[2];    // [S1S2,T]
    const int*   edge_src  = (const int*)d_in[3];    // [E]
    // d_in[4] edge_dst: known structure repeat(arange(B), DEG)
    const float* user_emb  = (const float*)d_in[5];
    const float* item_emb  = (const float*)d_in[6];
    const float* W_ih      = (const float*)d_in[7];
    const float* W_hh      = (const float*)d_in[8];
    const float* b_ih      = (const float*)d_in[9];
    const float* b_hh      = (const float*)d_in[10];
    const float* W1        = (const float*)d_in[11];
    const float* fc_W      = (const float*)d_in[12];
    const float* fc_b      = (const float*)d_in[13];
    const float* W2        = (const float*)d_in[14];
    float* out = (float*)d_out;

    char* ws = (char*)d_ws;
    float*    out_h  = (float*)(ws);                    // [B,D]        204800 B
    float*    ls1    = (float*)(ws + 204800);           // [S1S2,D]     200000 B
    unsigned* sr_u   = (unsigned*)(ws + 404800);        // [B,32]       131072 B
    unsigned* item_u = (unsigned*)(ws + 535872);        // [NIPAD,32]  6406144 B

    hipLaunchKernelGGL(fused_front_kernel,
                       dim3(BATCH + S1S2 + PREP_BLKS), dim3(256), 0, stream,
                       sess, nodes, fsess, user_emb, item_emb,
                       W_ih, W_hh, b_ih, b_hh, W1, out_h, ls1, item_u);
    hipLaunchKernelGGL(gat_sr_kernel, dim3(BATCH), dim3(64), 0, stream,
                       out_h, ls1, edge_src, fc_W, fc_b, W2, sr_u);
    hipLaunchKernelGGL(logits_mfma_kernel,
                       dim3((BATCH / 16) * CHUNKS_PAD), dim3(256), 0, stream,
                       (const unsigned short*)sr_u, (const unsigned short*)item_u, out);
}